// Round 1
// baseline (783.039 us; speedup 1.0000x reference)
//
#include <hip/hip_runtime.h>
#include <math.h>

#define EPS 1e-10f

// Workspace layout:
//   double acc[4]   : cls_sum, bbox_sum, sigma_sum, neg_sum
//   int    ia[2]    : n_pos, last_pos (position in valid array)

__global__ void init_ws_kernel(double* __restrict__ acc, int* __restrict__ ia) {
    acc[0] = 0.0; acc[1] = 0.0; acc[2] = 0.0; acc[3] = 0.0;
    ia[0] = 0;
    ia[1] = -1;
}

__global__ __launch_bounds__(256) void rpn_loss_main(
    const float4* __restrict__ bbox,     // [N,4] as float4
    const float2* __restrict__ logits,   // [N,2] as float2
    const float4* __restrict__ sigma,    // [N,4]
    const float4* __restrict__ gt,       // [N,4]
    const int*    __restrict__ labels,   // [N]
    const int*    __restrict__ vidx,     // [V]
    int V,
    double* __restrict__ acc,
    int* __restrict__ ia)
{
    double cls_s = 0.0, bbox_s = 0.0, sig_s = 0.0, neg_s = 0.0;
    int npos = 0;
    int lastpos = -1;

    int tid    = blockIdx.x * blockDim.x + threadIdx.x;
    int stride = gridDim.x * blockDim.x;

    for (int i = tid; i < V; i += stride) {
        int idx = vidx[i];
        int lbl = labels[idx];

        // ---- classification: -log_softmax(logits)[lbl], 2-class stable form
        float2 lg  = logits[idx];
        float l_p  = lbl ? lg.y : lg.x;   // picked logit
        float l_o  = lbl ? lg.x : lg.y;   // other logit
        float d    = l_o - l_p;
        // -logp = log(1 + exp(d)), numerically stable
        float closs = (d > 0.0f) ? (d + log1pf(expf(-d))) : log1pf(expf(d));
        cls_s += (double)closs;

        // ---- regression terms
        float4 p = bbox[idx];
        float4 t = gt[idx];
        float4 s = sigma[idx];

        float dx = p.x - t.x, dy = p.y - t.y, dz = p.z - t.z, dw = p.w - t.w;
        float i0 = 1.0f / (EPS + s.x);
        float i1 = 1.0f / (EPS + s.y);
        float i2 = 1.0f / (EPS + s.z);
        float i3 = 1.0f / (EPS + s.w);

        if (lbl == 1) {
            float per_bbox = 0.5f * dx * dx * i0 + 0.5f * dy * dy * i1
                           + 0.5f * dz * dz * i2 + 0.5f * dw * dw * i3;
            float per_sigma = 0.5f * (logf(EPS + s.x) + logf(EPS + s.y)
                                    + logf(EPS + s.z) + logf(EPS + s.w));
            bbox_s += (double)per_bbox;
            sig_s  += (double)per_sigma;
            npos   += 1;
            lastpos = i;   // i increases within the loop; final value is the max
        } else {
            neg_s += (double)(i0 + i1 + i2 + i3);
        }
    }

    // ---- wave-64 reduction
    for (int off = 32; off > 0; off >>= 1) {
        cls_s  += __shfl_down(cls_s,  off);
        bbox_s += __shfl_down(bbox_s, off);
        sig_s  += __shfl_down(sig_s,  off);
        neg_s  += __shfl_down(neg_s,  off);
        npos   += __shfl_down(npos,   off);
        int lp  = __shfl_down(lastpos, off);
        lastpos = lp > lastpos ? lp : lastpos;
    }

    if ((threadIdx.x & 63) == 0) {
        atomicAdd(&acc[0], cls_s);
        atomicAdd(&acc[1], bbox_s);
        atomicAdd(&acc[2], sig_s);
        atomicAdd(&acc[3], neg_s);
        atomicAdd(&ia[0], npos);
        atomicMax(&ia[1], lastpos);
    }
}

__global__ void finalize_kernel(
    const double* __restrict__ acc,
    const int* __restrict__ ia,
    const int* __restrict__ vidx,
    const float4* __restrict__ bbox,
    const float4* __restrict__ gt,
    int V,
    float* __restrict__ out)
{
    int npos = ia[0];
    int lastpos = ia[1];
    float n_pos = (float)npos;
    float n_neg = (float)(V - npos);

    out[0] = (float)(acc[0] / (double)V);   // class_loss (mean over V)
    out[1] = (float)(acc[1] / (double)npos);          // reg_loss_bbox
    out[2] = (float)(acc[2] / (double)npos);          // reg_loss_sigma
    out[3] = (float)(acc[3] / (double)(V - npos));    // reg_loss_neg

    // reg_loss_bbox_only: sq-sum of the LAST positive valid anchor / n_pos
    float v4 = 0.0f;
    if (lastpos >= 0) {
        int idx = vidx[lastpos];
        float4 p = bbox[idx];
        float4 t = gt[idx];
        float dx = p.x - t.x, dy = p.y - t.y, dz = p.z - t.z, dw = p.w - t.w;
        float sumsq = 0.5f * (dx * dx + dy * dy + dz * dz + dw * dw);
        v4 = sumsq / n_pos;
    }
    out[4] = v4;
    (void)n_neg;
}

extern "C" void kernel_launch(void* const* d_in, const int* in_sizes, int n_in,
                              void* d_out, int out_size, void* d_ws, size_t ws_size,
                              hipStream_t stream) {
    const float* bbox_pred    = (const float*)d_in[0];  // [1, N, 4]
    const float* class_logits = (const float*)d_in[1];  // [1, N, 2]
    const float* sigma_pred   = (const float*)d_in[2];  // [1, N, 4]
    const float* gt_bbox      = (const float*)d_in[3];  // [1, N, 4]
    const int*   gt_label     = (const int*)d_in[4];    // [1, N]
    const int*   valid_idx    = (const int*)d_in[5];    // [V]

    int V = in_sizes[5];

    double* acc = (double*)d_ws;
    int*    ia  = (int*)((char*)d_ws + 4 * sizeof(double));

    init_ws_kernel<<<1, 1, 0, stream>>>(acc, ia);

    int blocks = (V + 255) / 256;
    if (blocks > 2048) blocks = 2048;
    rpn_loss_main<<<blocks, 256, 0, stream>>>(
        (const float4*)bbox_pred,
        (const float2*)class_logits,
        (const float4*)sigma_pred,
        (const float4*)gt_bbox,
        gt_label, valid_idx, V, acc, ia);

    finalize_kernel<<<1, 1, 0, stream>>>(
        acc, ia, valid_idx,
        (const float4*)bbox_pred,
        (const float4*)gt_bbox,
        V, (float*)d_out);
}

// Round 3
// 234.087 us; speedup vs baseline: 3.3451x; 3.3451x over previous
//
#include <hip/hip_runtime.h>
#include <math.h>

#define EPS 1e-10f
#define MAIN_BLOCK 256
#define MAX_BLOCKS 2048

// Workspace layout (per block, no atomics anywhere):
//   double partials[MAX_BLOCKS][4]  : cls_sum, bbox_sum, sigma_sum, neg_sum
//   int    pnpos[MAX_BLOCKS]
//   int    plastpos[MAX_BLOCKS]

__global__ __launch_bounds__(MAIN_BLOCK) void rpn_loss_main(
    const float4* __restrict__ bbox,     // [N,4] as float4
    const float2* __restrict__ logits,   // [N,2] as float2
    const float4* __restrict__ sigma,    // [N,4]
    const float4* __restrict__ gt,       // [N,4]
    const int*    __restrict__ labels,   // [N]
    const int*    __restrict__ vidx,     // [V]
    int V,
    double* __restrict__ partials,       // [nb*4]
    int* __restrict__ pnpos,             // [nb]
    int* __restrict__ plastpos)          // [nb]
{
    double cls_s = 0.0, bbox_s = 0.0, sig_s = 0.0, neg_s = 0.0;
    int npos = 0;
    int lastpos = -1;

    int tid    = blockIdx.x * blockDim.x + threadIdx.x;
    int stride = gridDim.x * blockDim.x;

    for (int i = tid; i < V; i += stride) {
        int idx = vidx[i];
        int lbl = labels[idx];

        // ---- classification: -log_softmax(logits)[lbl], 2-class stable form
        float2 lg  = logits[idx];
        float l_p  = lbl ? lg.y : lg.x;   // picked logit
        float l_o  = lbl ? lg.x : lg.y;   // other logit
        float d    = l_o - l_p;
        float closs = (d > 0.0f) ? (d + log1pf(expf(-d))) : log1pf(expf(d));
        cls_s += (double)closs;

        // ---- regression terms
        float4 p = bbox[idx];
        float4 t = gt[idx];
        float4 s = sigma[idx];

        float dx = p.x - t.x, dy = p.y - t.y, dz = p.z - t.z, dw = p.w - t.w;
        float i0 = 1.0f / (EPS + s.x);
        float i1 = 1.0f / (EPS + s.y);
        float i2 = 1.0f / (EPS + s.z);
        float i3 = 1.0f / (EPS + s.w);

        if (lbl == 1) {
            float per_bbox = 0.5f * dx * dx * i0 + 0.5f * dy * dy * i1
                           + 0.5f * dz * dz * i2 + 0.5f * dw * dw * i3;
            float per_sigma = 0.5f * (logf(EPS + s.x) + logf(EPS + s.y)
                                    + logf(EPS + s.z) + logf(EPS + s.w));
            bbox_s += (double)per_bbox;
            sig_s  += (double)per_sigma;
            npos   += 1;
            lastpos = i;
        } else {
            neg_s += (double)(i0 + i1 + i2 + i3);
        }
    }

    // ---- wave-64 shuffle reduction
    for (int off = 32; off > 0; off >>= 1) {
        cls_s  += __shfl_down(cls_s,  off);
        bbox_s += __shfl_down(bbox_s, off);
        sig_s  += __shfl_down(sig_s,  off);
        neg_s  += __shfl_down(neg_s,  off);
        npos   += __shfl_down(npos,   off);
        int lp  = __shfl_down(lastpos, off);
        lastpos = lp > lastpos ? lp : lastpos;
    }

    // ---- cross-wave reduction via LDS (4 waves/block)
    __shared__ double s_acc[4][4];
    __shared__ int    s_np[4];
    __shared__ int    s_lp[4];
    int wave = threadIdx.x >> 6;
    if ((threadIdx.x & 63) == 0) {
        s_acc[wave][0] = cls_s;
        s_acc[wave][1] = bbox_s;
        s_acc[wave][2] = sig_s;
        s_acc[wave][3] = neg_s;
        s_np[wave] = npos;
        s_lp[wave] = lastpos;
    }
    __syncthreads();
    if (threadIdx.x == 0) {
        double c = 0, b = 0, sg = 0, ng = 0;
        int np = 0, lp = -1;
        for (int w = 0; w < 4; ++w) {
            c  += s_acc[w][0];
            b  += s_acc[w][1];
            sg += s_acc[w][2];
            ng += s_acc[w][3];
            np += s_np[w];
            lp  = s_lp[w] > lp ? s_lp[w] : lp;
        }
        partials[blockIdx.x * 4 + 0] = c;
        partials[blockIdx.x * 4 + 1] = b;
        partials[blockIdx.x * 4 + 2] = sg;
        partials[blockIdx.x * 4 + 3] = ng;
        pnpos[blockIdx.x]    = np;
        plastpos[blockIdx.x] = lp;
    }
}

__global__ __launch_bounds__(256) void finalize_kernel(
    const double* __restrict__ partials,
    const int* __restrict__ pnpos,
    const int* __restrict__ plastpos,
    int nb,
    const int* __restrict__ vidx,
    const float4* __restrict__ bbox,
    const float4* __restrict__ gt,
    int V,
    float* __restrict__ out)
{
    double cls_s = 0.0, bbox_s = 0.0, sig_s = 0.0, neg_s = 0.0;
    int npos = 0, lastpos = -1;

    for (int i = threadIdx.x; i < nb; i += 256) {
        cls_s  += partials[i * 4 + 0];
        bbox_s += partials[i * 4 + 1];
        sig_s  += partials[i * 4 + 2];
        neg_s  += partials[i * 4 + 3];
        npos   += pnpos[i];
        int lp  = plastpos[i];
        lastpos = lp > lastpos ? lp : lastpos;
    }

    for (int off = 32; off > 0; off >>= 1) {
        cls_s  += __shfl_down(cls_s,  off);
        bbox_s += __shfl_down(bbox_s, off);
        sig_s  += __shfl_down(sig_s,  off);
        neg_s  += __shfl_down(neg_s,  off);
        npos   += __shfl_down(npos,   off);
        int lp  = __shfl_down(lastpos, off);
        lastpos = lp > lastpos ? lp : lastpos;
    }

    __shared__ double s_acc[4][4];
    __shared__ int    s_np[4];
    __shared__ int    s_lp[4];
    int wave = threadIdx.x >> 6;
    if ((threadIdx.x & 63) == 0) {
        s_acc[wave][0] = cls_s;
        s_acc[wave][1] = bbox_s;
        s_acc[wave][2] = sig_s;
        s_acc[wave][3] = neg_s;
        s_np[wave] = npos;
        s_lp[wave] = lastpos;
    }
    __syncthreads();

    if (threadIdx.x == 0) {
        double c = 0, b = 0, sg = 0, ng = 0;
        int np = 0, lp = -1;
        for (int w = 0; w < 4; ++w) {
            c  += s_acc[w][0];
            b  += s_acc[w][1];
            sg += s_acc[w][2];
            ng += s_acc[w][3];
            np += s_np[w];
            lp  = s_lp[w] > lp ? s_lp[w] : lp;
        }
        float n_pos = (float)np;

        out[0] = (float)(c / (double)V);
        out[1] = (float)(b / (double)np);
        out[2] = (float)(sg / (double)np);
        out[3] = (float)(ng / (double)(V - np));

        float v4 = 0.0f;
        if (lp >= 0) {
            int idx = vidx[lp];
            float4 pp = bbox[idx];
            float4 tt = gt[idx];
            float ddx = pp.x - tt.x, ddy = pp.y - tt.y;
            float ddz = pp.z - tt.z, ddw = pp.w - tt.w;
            v4 = 0.5f * (ddx * ddx + ddy * ddy + ddz * ddz + ddw * ddw) / n_pos;
        }
        out[4] = v4;
    }
}

extern "C" void kernel_launch(void* const* d_in, const int* in_sizes, int n_in,
                              void* d_out, int out_size, void* d_ws, size_t ws_size,
                              hipStream_t stream) {
    const float* bbox_pred    = (const float*)d_in[0];  // [1, N, 4]
    const float* class_logits = (const float*)d_in[1];  // [1, N, 2]
    const float* sigma_pred   = (const float*)d_in[2];  // [1, N, 4]
    const float* gt_bbox      = (const float*)d_in[3];  // [1, N, 4]
    const int*   gt_label     = (const int*)d_in[4];    // [1, N]
    const int*   valid_idx    = (const int*)d_in[5];    // [V]

    int V = in_sizes[5];

    double* partials = (double*)d_ws;
    int*    pnpos    = (int*)((char*)d_ws + MAX_BLOCKS * 4 * sizeof(double));
    int*    plastpos = pnpos + MAX_BLOCKS;

    int blocks = (V + MAIN_BLOCK - 1) / MAIN_BLOCK;
    if (blocks > MAX_BLOCKS) blocks = MAX_BLOCKS;

    rpn_loss_main<<<blocks, MAIN_BLOCK, 0, stream>>>(
        (const float4*)bbox_pred,
        (const float2*)class_logits,
        (const float4*)sigma_pred,
        (const float4*)gt_bbox,
        gt_label, valid_idx, V, partials, pnpos, plastpos);

    finalize_kernel<<<1, 256, 0, stream>>>(
        partials, pnpos, plastpos, blocks,
        valid_idx,
        (const float4*)bbox_pred,
        (const float4*)gt_bbox,
        V, (float*)d_out);
}